// Round 1
// baseline (643.180 us; speedup 1.0000x reference)
//
#include <hip/hip_runtime.h>
#include <math.h>

#define BB 64
#define NN 4096
#define KS 8
#define DD 64
#define LN_EPS 1e-5f
#define EPS 1e-8f

// workspace offsets (in floats)
#define OFF_KT    0L          // k transposed [b][d][n]    16777216
#define OFF_V     16777216L   // v row-major  [b][n][d]    16777216
#define OFF_QT    33554432L   // q  [b][d][k], pre-scaled  32768
#define OFF_ACC   33587200L   // acc [b][k][d]             32768
#define OFF_COL   33619968L   // colsum [b][k]             512
#define OFF_SLOTS 33620480L   // slots [b][k][d]           32768
#define OFF_WIHT  33653248L   // w_ih^T [64][192]          12288
#define OFF_WHHT  33665536L   // w_hh^T [64][192]          12288
#define OFF_W1T   33677824L   // mlp_w1^T [64][128]        8192
#define OFF_W2T   33686016L   // mlp_w2^T [128][64]        8192
#define OFF_WQT   33694208L   // Wq^T [64][64]             4096

__device__ __forceinline__ float wredsum(float v) {
#pragma unroll
  for (int off = 32; off > 0; off >>= 1) v += __shfl_xor(v, off);
  return v;
}

// ---------------------------------------------------------------------------
// K0: transpose small weights once so later lane-varying reads are coalesced.
// grid 176 x 256 == 45056 threads == total elements.
__global__ __launch_bounds__(256) void k_prep(
    const float* __restrict__ w_ih, const float* __restrict__ w_hh,
    const float* __restrict__ w1, const float* __restrict__ w2,
    const float* __restrict__ Wq,
    float* __restrict__ wihT, float* __restrict__ whhT,
    float* __restrict__ w1T, float* __restrict__ w2T, float* __restrict__ wqT)
{
  int idx = blockIdx.x * 256 + threadIdx.x;
  if (idx < 12288) {
    int j = idx >> 6, f = idx & 63;
    wihT[f * 192 + j] = w_ih[idx];
  } else if (idx < 24576) {
    int i = idx - 12288; int j = i >> 6, f = i & 63;
    whhT[f * 192 + j] = w_hh[i];
  } else if (idx < 32768) {
    int i = idx - 24576; int j = i >> 6, f = i & 63;
    w1T[f * 128 + j] = w1[i];
  } else if (idx < 40960) {
    int i = idx - 32768; int d = i >> 7, j = i & 127;
    w2T[j * 64 + d] = w2[i];
  } else if (idx < 45056) {
    int i = idx - 40960; int e = i >> 6, d = i & 63;
    wqT[d * 64 + e] = Wq[i];
  }
}

// ---------------------------------------------------------------------------
// K1: fused LayerNorm + K/V projection.
// block = 256 (4 waves), tile = 64 rows; grid = 4096.
// Stage 1 (lane=f): LN with coalesced loads, xn -> LDS (pad 65).
// Stage 2 (lane=n): weights via uniform (SGPR) loads, 1 FMA/MAC.
// k stored [b][d][n] directly coalesced; v transposed through LDS -> [b][n][d].
__global__ __launch_bounds__(256) void k_ln_project(
    const float* __restrict__ inp, const float* __restrict__ Wk,
    const float* __restrict__ Wv, const float* __restrict__ g,
    const float* __restrict__ bbv,
    float* __restrict__ k_t, float* __restrict__ v)
{
  __shared__ float xn[64 * 65];
  __shared__ float vstage[64 * 65];
  const int tid = threadIdx.x;
  const int lane = tid & 63;
  const int wave = tid >> 6;
  const int tile = blockIdx.x;        // 0..4095
  const int b = tile >> 6;            // 64 tiles per batch
  const int n0 = (tile & 63) << 6;
  const float* rowbase = inp + (((long)b * NN + n0) << 6);
  const float gg = g[lane];
  const float bv = bbv[lane];

  // stage 1: each wave LayerNorms 16 rows, lane = feature
  for (int r = 0; r < 16; ++r) {
    const int lrow = wave * 16 + r;
    float x = rowbase[lrow * 64 + lane];
    float mu = wredsum(x) * (1.f / 64.f);
    float dx = x - mu;
    float var = wredsum(dx * dx) * (1.f / 64.f);
    xn[lrow * 65 + lane] = dx * rsqrtf(var + LN_EPS) * gg + bv;
  }
  __syncthreads();

  // stage 2: lane = local row; this wave computes d in [wave*16, wave*16+16)
  float xr[64];
#pragma unroll
  for (int f = 0; f < 64; ++f) xr[f] = xn[lane * 65 + f];  // 2-way bank alias: free

  const int d0 = __builtin_amdgcn_readfirstlane(wave * 16);
  for (int dd = 0; dd < 16; ++dd) {
    const int d = d0 + dd;                       // wave-uniform -> s_load weights
    const float* wkr = Wk + d * 64;
    const float* wvr = Wv + d * 64;
    float ka = 0.f, va = 0.f;
#pragma unroll
    for (int f = 0; f < 64; ++f) {
      ka = fmaf(xr[f], wkr[f], ka);
      va = fmaf(xr[f], wvr[f], va);
    }
    k_t[((long)(b * 64 + d)) * NN + n0 + lane] = ka;  // coalesced over n
    vstage[d * 65 + lane] = va;
  }
  __syncthreads();

  // write v row-major [b][n][d], coalesced over d
  for (int i = 0; i < 16; ++i) {
    const int n = wave + i * 4;
    v[(((long)b * NN + n0 + n) << 6) + lane] = vstage[lane * 65 + n] * 0.f
        + vstage[lane * 65 + n];  // read pattern: bank (lane+n)%32, conflict-free
  }
}

// ---------------------------------------------------------------------------
// K2: slots init + LN + q0 (+ zero acc/colsum). One wave per (b,k) row.
// grid 128 x 256.
__global__ __launch_bounds__(256) void k_init(
    const float* __restrict__ noise, const float* __restrict__ smu,
    const float* __restrict__ slsig, const float* __restrict__ wqT,
    const float* __restrict__ g_sl, const float* __restrict__ b_sl,
    float* __restrict__ slots, float* __restrict__ q_t,
    float* __restrict__ acc, float* __restrict__ colsum)
{
  __shared__ float S[4][64];
  const int tid = threadIdx.x, lane = tid & 63, wave = tid >> 6;
  const int row = blockIdx.x * 4 + wave;   // 0..511
  const int b = row >> 3, ks = row & 7;

  float s0 = fmaf(expf(slsig[lane]), noise[row * 64 + lane], smu[lane]);
  slots[row * 64 + lane] = s0;
  acc[row * 64 + lane] = 0.f;
  if (lane == 0) colsum[row] = 0.f;

  float mu = wredsum(s0) * (1.f / 64.f);
  float dx = s0 - mu;
  float var = wredsum(dx * dx) * (1.f / 64.f);
  float sn = dx * rsqrtf(var + LN_EPS) * g_sl[lane] + b_sl[lane];
  S[wave][lane] = sn;
  __syncthreads();
  float qe = 0.f;
#pragma unroll 16
  for (int d = 0; d < 64; ++d) qe = fmaf(S[wave][d], wqT[d * 64 + lane], qe);
  q_t[b * 512 + lane * 8 + ks] = qe * 0.125f;   // pre-scaled, layout [b][d][k]
}

// ---------------------------------------------------------------------------
// K3: fused attention pass. One wave processes 2 chunks of 64 n.
// Phase A (lane=n): logits via q from SGPRs, softmax over K=8, attn -> LDS.
// Phase B (lane=d): acc[k][d] += attn * v, v read coalesced from [b][n][d].
// grid 512 (8 blocks per batch) x 256.
__global__ __launch_bounds__(256) void k_attn(
    const float* __restrict__ k_t, const float* __restrict__ v,
    const float* __restrict__ q_t,
    float* __restrict__ acc, float* __restrict__ colsum)
{
  __shared__ float attnLds[4][64 * 8];
  const int tid = threadIdx.x;
  const int lane = tid & 63;
  const int wave = tid >> 6;
  const int b = blockIdx.x >> 3;
  const int blk8 = blockIdx.x & 7;
  const float* qb = q_t + b * 512;   // uniform -> scalar loads

  float accr[8], colp[8];
#pragma unroll
  for (int i = 0; i < 8; ++i) { accr[i] = 0.f; colp[i] = 0.f; }

  for (int c = 0; c < 2; ++c) {
    const int chunk = (blk8 * 4 + wave) * 2 + c;  // 0..63
    const int n0 = chunk * 64;

    // ---- Phase A ----
    float logit[8];
#pragma unroll
    for (int i = 0; i < 8; ++i) logit[i] = 0.f;
    const float* kb = k_t + (long)b * (64L * NN) + n0 + lane;
#pragma unroll
    for (int d = 0; d < 64; ++d) {
      float kd = kb[(long)d * NN];
#pragma unroll
      for (int kk = 0; kk < 8; ++kk)
        logit[kk] = fmaf(kd, qb[d * 8 + kk], logit[kk]);
    }
    float m = logit[0];
#pragma unroll
    for (int kk = 1; kk < 8; ++kk) m = fmaxf(m, logit[kk]);
    float e[8]; float ssum = 0.f;
#pragma unroll
    for (int kk = 0; kk < 8; ++kk) { e[kk] = __expf(logit[kk] - m); ssum += e[kk]; }
    float inv = 1.f / ssum;
    float4 a0, a1;
    a0.x = fmaf(e[0], inv, EPS); a0.y = fmaf(e[1], inv, EPS);
    a0.z = fmaf(e[2], inv, EPS); a0.w = fmaf(e[3], inv, EPS);
    a1.x = fmaf(e[4], inv, EPS); a1.y = fmaf(e[5], inv, EPS);
    a1.z = fmaf(e[6], inv, EPS); a1.w = fmaf(e[7], inv, EPS);
    colp[0] += a0.x; colp[1] += a0.y; colp[2] += a0.z; colp[3] += a0.w;
    colp[4] += a1.x; colp[5] += a1.y; colp[6] += a1.z; colp[7] += a1.w;
    ((float4*)&attnLds[wave][lane * 8])[0] = a0;
    ((float4*)&attnLds[wave][lane * 8])[1] = a1;
    __syncthreads();

    // ---- Phase B ----
    const float* vb = v + ((long)b * NN + n0) * 64 + lane;
#pragma unroll 8
    for (int n = 0; n < 64; ++n) {
      float vd = vb[(long)n * 64];
      const float4 aa0 = ((const float4*)&attnLds[wave][n * 8])[0];
      const float4 aa1 = ((const float4*)&attnLds[wave][n * 8])[1];
      accr[0] = fmaf(aa0.x, vd, accr[0]);
      accr[1] = fmaf(aa0.y, vd, accr[1]);
      accr[2] = fmaf(aa0.z, vd, accr[2]);
      accr[3] = fmaf(aa0.w, vd, accr[3]);
      accr[4] = fmaf(aa1.x, vd, accr[4]);
      accr[5] = fmaf(aa1.y, vd, accr[5]);
      accr[6] = fmaf(aa1.z, vd, accr[6]);
      accr[7] = fmaf(aa1.w, vd, accr[7]);
    }
    __syncthreads();
  }

#pragma unroll
  for (int kk = 0; kk < 8; ++kk) colp[kk] = wredsum(colp[kk]);
#pragma unroll
  for (int kk = 0; kk < 8; ++kk)
    atomicAdd(&acc[(b * 8 + kk) * 64 + lane], accr[kk]);
#pragma unroll
  for (int kk = 0; kk < 8; ++kk)
    if (lane == kk) atomicAdd(&colsum[b * 8 + kk], colp[kk]);
}

// ---------------------------------------------------------------------------
// K4: updates -> GRU -> LN -> MLP -> residual; also emits next-iter q and
// zeroes acc/colsum. One wave per (b,k) row. grid 128 x 256.
__global__ __launch_bounds__(256) void k_update(
    float* __restrict__ acc, float* __restrict__ colsum,
    float* __restrict__ slots,
    const float* __restrict__ wihT, const float* __restrict__ whhT,
    const float* __restrict__ w1T, const float* __restrict__ w2T,
    const float* __restrict__ wqT,
    const float* __restrict__ b_ih, const float* __restrict__ b_hh,
    const float* __restrict__ mb1, const float* __restrict__ mb2,
    const float* __restrict__ g_ml, const float* __restrict__ b_ml,
    const float* __restrict__ g_sl, const float* __restrict__ b_sl,
    float* __restrict__ q_t, float* __restrict__ dout)
{
  __shared__ float S[4][256];
  const int tid = threadIdx.x, lane = tid & 63, wave = tid >> 6;
  const int row = blockIdx.x * 4 + wave;   // 0..511
  const int b = row >> 3, ks = row & 7;

  const float csum = colsum[row];
  const float u = acc[row * 64 + lane] / csum;
  const float h = slots[row * 64 + lane];
  acc[row * 64 + lane] = 0.f;            // ready for next k_attn
  if (lane == 0) colsum[row] = 0.f;

  float* Su = &S[wave][0];
  float* Sh = &S[wave][64];
  Su[lane] = u; Sh[lane] = h;
  __syncthreads();

  float gir = b_ih[lane], giz = b_ih[64 + lane], gin = b_ih[128 + lane];
  float ghr = b_hh[lane], ghz = b_hh[64 + lane], ghn = b_hh[128 + lane];
#pragma unroll 4
  for (int f = 0; f < 64; ++f) {
    const float uf = Su[f], hf = Sh[f];
    gir = fmaf(uf, wihT[f * 192 + lane], gir);
    giz = fmaf(uf, wihT[f * 192 + 64 + lane], giz);
    gin = fmaf(uf, wihT[f * 192 + 128 + lane], gin);
    ghr = fmaf(hf, whhT[f * 192 + lane], ghr);
    ghz = fmaf(hf, whhT[f * 192 + 64 + lane], ghz);
    ghn = fmaf(hf, whhT[f * 192 + 128 + lane], ghn);
  }
  const float r = 1.f / (1.f + expf(-(gir + ghr)));
  const float z = 1.f / (1.f + expf(-(giz + ghz)));
  const float nn = tanhf(fmaf(r, ghn, gin));
  const float hnew = (1.f - z) * nn + z * h;

  // LN (mlp)
  float mu = wredsum(hnew) * (1.f / 64.f);
  float dx = hnew - mu;
  float var = wredsum(dx * dx) * (1.f / 64.f);
  const float ln = dx * rsqrtf(var + LN_EPS) * g_ml[lane] + b_ml[lane];
  float* Sln = &S[wave][128];
  Sln[lane] = ln;
  __syncthreads();

  float h1a = mb1[lane], h1b = mb1[64 + lane];
#pragma unroll 4
  for (int f = 0; f < 64; ++f) {
    const float lf = Sln[f];
    h1a = fmaf(lf, w1T[f * 128 + lane], h1a);
    h1b = fmaf(lf, w1T[f * 128 + 64 + lane], h1b);
  }
  h1a = fmaxf(h1a, 0.f); h1b = fmaxf(h1b, 0.f);
  __syncthreads();                         // done reading Su/Sh region
  float* Shid = &S[wave][0];
  Shid[lane] = h1a; Shid[64 + lane] = h1b;
  __syncthreads();

  float o = mb2[lane];
#pragma unroll 4
  for (int j = 0; j < 128; ++j) o = fmaf(Shid[j], w2T[j * 64 + lane], o);
  const float snew = hnew + o;
  slots[row * 64 + lane] = snew;
  if (dout) dout[row * 64 + lane] = snew;

  // next-iteration q = LN_slots(snew) @ Wq^T * D^-0.5
  float mu2 = wredsum(snew) * (1.f / 64.f);
  float dx2 = snew - mu2;
  float v2 = wredsum(dx2 * dx2) * (1.f / 64.f);
  const float sq = dx2 * rsqrtf(v2 + LN_EPS) * g_sl[lane] + b_sl[lane];
  __syncthreads();                         // done reading Sln
  float* Ssq = &S[wave][128];
  Ssq[lane] = sq;
  __syncthreads();
  float qe = 0.f;
#pragma unroll 16
  for (int d = 0; d < 64; ++d) qe = fmaf(Ssq[d], wqT[d * 64 + lane], qe);
  q_t[b * 512 + lane * 8 + ks] = qe * 0.125f;
}

// ---------------------------------------------------------------------------
extern "C" void kernel_launch(void* const* d_in, const int* in_sizes, int n_in,
                              void* d_out, int out_size, void* d_ws, size_t ws_size,
                              hipStream_t stream) {
  const float* inp   = (const float*)d_in[0];
  const float* noise = (const float*)d_in[1];
  const float* smu   = (const float*)d_in[2];
  const float* slsig = (const float*)d_in[3];
  const float* Wq    = (const float*)d_in[4];
  const float* Wk    = (const float*)d_in[5];
  const float* Wv    = (const float*)d_in[6];
  const float* w_ih  = (const float*)d_in[7];
  const float* w_hh  = (const float*)d_in[8];
  const float* b_ih  = (const float*)d_in[9];
  const float* b_hh  = (const float*)d_in[10];
  const float* w1    = (const float*)d_in[11];
  const float* b1    = (const float*)d_in[12];
  const float* w2    = (const float*)d_in[13];
  const float* b2    = (const float*)d_in[14];
  const float* g_in  = (const float*)d_in[15];
  const float* bi_in = (const float*)d_in[16];
  const float* g_sl  = (const float*)d_in[17];
  const float* bi_sl = (const float*)d_in[18];
  const float* g_ml  = (const float*)d_in[19];
  const float* bi_ml = (const float*)d_in[20];

  float* ws   = (float*)d_ws;
  float* kt   = ws + OFF_KT;
  float* vv   = ws + OFF_V;
  float* qt   = ws + OFF_QT;
  float* ac   = ws + OFF_ACC;
  float* cs   = ws + OFF_COL;
  float* sl   = ws + OFF_SLOTS;
  float* wihT = ws + OFF_WIHT;
  float* whhT = ws + OFF_WHHT;
  float* w1T  = ws + OFF_W1T;
  float* w2T  = ws + OFF_W2T;
  float* wqT  = ws + OFF_WQT;

  k_prep<<<176, 256, 0, stream>>>(w_ih, w_hh, w1, w2, Wq, wihT, whhT, w1T, w2T, wqT);
  k_ln_project<<<4096, 256, 0, stream>>>(inp, Wk, Wv, g_in, bi_in, kt, vv);
  k_init<<<128, 256, 0, stream>>>(noise, smu, slsig, wqT, g_sl, bi_sl, sl, qt, ac, cs);
  for (int it = 0; it < 3; ++it) {
    k_attn<<<512, 256, 0, stream>>>(kt, vv, qt, ac, cs);
    k_update<<<128, 256, 0, stream>>>(ac, cs, sl, wihT, whhT, w1T, w2T, wqT,
                                      b_ih, b_hh, b1, b2, g_ml, bi_ml, g_sl, bi_sl,
                                      qt, it == 2 ? (float*)d_out : nullptr);
  }
}

// Round 2
// 349.524 us; speedup vs baseline: 1.8402x; 1.8402x over previous
//
#include <hip/hip_runtime.h>
#include <math.h>

#define BB 64
#define NN 4096
#define KS 8
#define DD 64
#define LN_EPS 1e-5f
#define EPS 1e-8f

// workspace offsets (in floats)
#define OFF_KT    0L          // k transposed [b][d][n]    16777216
#define OFF_V     16777216L   // v row-major  [b][n][d]    16777216
#define OFF_QT    33554432L   // q  [b][d][k], pre-scaled  32768
#define OFF_ACC   33587200L   // acc [b][k][d]             32768
#define OFF_COL   33619968L   // colsum [b][k]             512
#define OFF_SLOTS 33620480L   // slots [b][k][d]           32768
#define OFF_WIHT  33653248L   // w_ih^T [64][192]          12288
#define OFF_WHHT  33665536L   // w_hh^T [64][192]          12288
#define OFF_W1T   33677824L   // mlp_w1^T [64][128]        8192
#define OFF_W2T   33686016L   // mlp_w2^T [128][64]        8192
#define OFF_WQT   33694208L   // Wq^T [64][64]             4096
#define OFF_WKV   33698304L   // wkv^T [f=64][k:64 | v:64] 8192

__device__ __forceinline__ float wredsum(float v) {
#pragma unroll
  for (int off = 32; off > 0; off >>= 1) v += __shfl_xor(v, off);
  return v;
}

// ---------------------------------------------------------------------------
// K0: transpose small weights once so later lane-varying (or s_load) reads
// are contiguous. grid 208 x 256 covers 53248 elements.
__global__ __launch_bounds__(256) void k_prep(
    const float* __restrict__ w_ih, const float* __restrict__ w_hh,
    const float* __restrict__ w1, const float* __restrict__ w2,
    const float* __restrict__ Wq,
    const float* __restrict__ Wk, const float* __restrict__ Wv,
    float* __restrict__ wihT, float* __restrict__ whhT,
    float* __restrict__ w1T, float* __restrict__ w2T, float* __restrict__ wqT,
    float* __restrict__ wkv)
{
  int idx = blockIdx.x * 256 + threadIdx.x;
  if (idx < 12288) {
    int j = idx >> 6, f = idx & 63;
    wihT[f * 192 + j] = w_ih[idx];
  } else if (idx < 24576) {
    int i = idx - 12288; int j = i >> 6, f = i & 63;
    whhT[f * 192 + j] = w_hh[i];
  } else if (idx < 32768) {
    int i = idx - 24576; int j = i >> 6, f = i & 63;
    w1T[f * 128 + j] = w1[i];
  } else if (idx < 40960) {
    int i = idx - 32768; int d = i >> 7, j = i & 127;
    w2T[j * 64 + d] = w2[i];
  } else if (idx < 45056) {
    int i = idx - 40960; int e = i >> 6, d = i & 63;
    wqT[d * 64 + e] = Wq[i];
  } else if (idx < 49152) {
    int i = idx - 45056; int d = i >> 6, f = i & 63;
    wkv[f * 128 + d] = Wk[i];
  } else if (idx < 53248) {
    int i = idx - 49152; int d = i >> 6, f = i & 63;
    wkv[f * 128 + 64 + d] = Wv[i];
  }
}

// ---------------------------------------------------------------------------
// K1: fused LayerNorm + K/V projection.
// block = 256 (4 waves), tile = 64 rows of n; grid = 4096.
// Stage 1 (lane=f): LN, xn -> LDS (row stride 68 floats: 16B-aligned rows,
//   (lane*68+f)%32 = (lane*4+f)%32 -> <=8-way alias only on the few b128s).
// Stage 2 (lane=n): wave w owns d in [16w,16w+16). 32 accumulators in VGPRs,
//   x via 16 ds_read_b128, weights via wave-uniform s_load from wkv[f][128]
//   (d0 = readfirstlane(16*wave) forces the scalar path).
__global__ __launch_bounds__(256) void k_ln_project(
    const float* __restrict__ inp, const float* __restrict__ wkv,
    const float* __restrict__ g, const float* __restrict__ bbv,
    float* __restrict__ k_t, float* __restrict__ v)
{
  __shared__ float xn[64 * 68];
  __shared__ float vstage[64 * 68];
  const int tid = threadIdx.x;
  const int lane = tid & 63;
  const int wave = tid >> 6;
  const int tile = blockIdx.x;        // 0..4095
  const int b = tile >> 6;
  const int n0 = (tile & 63) << 6;
  const float* rowbase = inp + (((long)b * NN + n0) << 6);
  const float gg = g[lane];
  const float bv = bbv[lane];

  for (int r = 0; r < 16; ++r) {
    const int lrow = wave * 16 + r;
    float x = rowbase[lrow * 64 + lane];
    float mu = wredsum(x) * (1.f / 64.f);
    float dx = x - mu;
    float var = wredsum(dx * dx) * (1.f / 64.f);
    xn[lrow * 68 + lane] = dx * rsqrtf(var + LN_EPS) * gg + bv;
  }
  __syncthreads();

  const int d0 = __builtin_amdgcn_readfirstlane(wave << 4);
  float kacc[16], vacc[16];
#pragma unroll
  for (int i = 0; i < 16; ++i) { kacc[i] = 0.f; vacc[i] = 0.f; }

  for (int f4 = 0; f4 < 64; f4 += 4) {
    const float4 xq = *(const float4*)&xn[lane * 68 + f4];
    const float* wrow = wkv + f4 * 128 + d0;    // wave-uniform -> s_load
#pragma unroll
    for (int j = 0; j < 4; ++j) {
      const float xf = (j == 0) ? xq.x : (j == 1) ? xq.y : (j == 2) ? xq.z : xq.w;
#pragma unroll
      for (int d = 0; d < 16; ++d) {
        kacc[d] = fmaf(xf, wrow[j * 128 + d], kacc[d]);
        vacc[d] = fmaf(xf, wrow[j * 128 + 64 + d], vacc[d]);
      }
    }
  }

#pragma unroll
  for (int d = 0; d < 16; ++d)
    k_t[((long)(b * 64 + d0 + d)) * NN + n0 + lane] = kacc[d];  // coalesced over n
#pragma unroll
  for (int d = 0; d < 16; ++d)
    vstage[(d0 + d) * 68 + lane] = vacc[d];
  __syncthreads();

  // write v row-major [b][n][d], coalesced over d=lane
#pragma unroll
  for (int i = 0; i < 16; ++i) {
    const int n = (wave << 4) + i;
    v[(((long)b * NN + n0 + n) << 6) + lane] = vstage[lane * 68 + n];
  }
}

// ---------------------------------------------------------------------------
// K2: slots init + LN + q0 (+ zero acc/colsum). One wave per (b,k) row.
// grid 128 x 256.
__global__ __launch_bounds__(256) void k_init(
    const float* __restrict__ noise, const float* __restrict__ smu,
    const float* __restrict__ slsig, const float* __restrict__ wqT,
    const float* __restrict__ g_sl, const float* __restrict__ b_sl,
    float* __restrict__ slots, float* __restrict__ q_t,
    float* __restrict__ acc, float* __restrict__ colsum)
{
  __shared__ float S[4][64];
  const int tid = threadIdx.x, lane = tid & 63, wave = tid >> 6;
  const int row = blockIdx.x * 4 + wave;   // 0..511
  const int b = row >> 3, ks = row & 7;

  float s0 = fmaf(expf(slsig[lane]), noise[row * 64 + lane], smu[lane]);
  slots[row * 64 + lane] = s0;
  acc[row * 64 + lane] = 0.f;
  if (lane == 0) colsum[row] = 0.f;

  float mu = wredsum(s0) * (1.f / 64.f);
  float dx = s0 - mu;
  float var = wredsum(dx * dx) * (1.f / 64.f);
  float sn = dx * rsqrtf(var + LN_EPS) * g_sl[lane] + b_sl[lane];
  S[wave][lane] = sn;
  __syncthreads();
  float qe = 0.f;
#pragma unroll 16
  for (int d = 0; d < 64; ++d) qe = fmaf(S[wave][d], wqT[d * 64 + lane], qe);
  q_t[b * 512 + lane * 8 + ks] = qe * 0.125f;   // pre-scaled, layout [b][d][k]
}

// ---------------------------------------------------------------------------
// K3: fused attention pass. ONE 64-n chunk per wave (4096 waves -> 16/CU).
// Phase A (lane=n): logits via q from SGPRs, softmax over K=8, attn -> LDS.
// Phase B (lane=d): acc[k][d] += attn * v, v read coalesced from [b][n][d].
// Block-level LDS reduction before atomics (4x fewer atomic adds).
// grid 1024 (16 blocks per batch) x 256.
__global__ __launch_bounds__(256) void k_attn(
    const float* __restrict__ k_t, const float* __restrict__ v,
    const float* __restrict__ q_t,
    float* __restrict__ acc, float* __restrict__ colsum)
{
  __shared__ float attnLds[4][64 * 8];
  __shared__ float accLds[4][8][64];
  __shared__ float colLds[4][8];
  const int tid = threadIdx.x;
  const int lane = tid & 63;
  const int wave = tid >> 6;
  const int b = blockIdx.x >> 4;
  const int chunk = ((blockIdx.x & 15) << 2) | wave;  // 0..63
  const int n0 = chunk << 6;
  const float* qb = q_t + b * 512;   // uniform -> scalar loads

  // ---- Phase A ----
  float logit[8];
#pragma unroll
  for (int i = 0; i < 8; ++i) logit[i] = 0.f;
  const float* kb = k_t + (long)b * (64L * NN) + n0 + lane;
#pragma unroll
  for (int d = 0; d < 64; ++d) {
    float kd = kb[(long)d * NN];
#pragma unroll
    for (int kk = 0; kk < 8; ++kk)
      logit[kk] = fmaf(kd, qb[d * 8 + kk], logit[kk]);
  }
  float m = logit[0];
#pragma unroll
  for (int kk = 1; kk < 8; ++kk) m = fmaxf(m, logit[kk]);
  float e[8]; float ssum = 0.f;
#pragma unroll
  for (int kk = 0; kk < 8; ++kk) { e[kk] = __expf(logit[kk] - m); ssum += e[kk]; }
  float inv = 1.f / ssum;
  float4 a0, a1;
  a0.x = fmaf(e[0], inv, EPS); a0.y = fmaf(e[1], inv, EPS);
  a0.z = fmaf(e[2], inv, EPS); a0.w = fmaf(e[3], inv, EPS);
  a1.x = fmaf(e[4], inv, EPS); a1.y = fmaf(e[5], inv, EPS);
  a1.z = fmaf(e[6], inv, EPS); a1.w = fmaf(e[7], inv, EPS);
  float colp[8];
  colp[0] = a0.x; colp[1] = a0.y; colp[2] = a0.z; colp[3] = a0.w;
  colp[4] = a1.x; colp[5] = a1.y; colp[6] = a1.z; colp[7] = a1.w;
  ((float4*)&attnLds[wave][lane * 8])[0] = a0;
  ((float4*)&attnLds[wave][lane * 8])[1] = a1;
  __syncthreads();

  // ---- Phase B ----
  float accr[8];
#pragma unroll
  for (int i = 0; i < 8; ++i) accr[i] = 0.f;
  const float* vb = v + ((long)b * NN + n0) * 64 + lane;
#pragma unroll 8
  for (int n = 0; n < 64; ++n) {
    float vd = vb[(long)n * 64];
    const float4 aa0 = ((const float4*)&attnLds[wave][n * 8])[0];
    const float4 aa1 = ((const float4*)&attnLds[wave][n * 8])[1];
    accr[0] = fmaf(aa0.x, vd, accr[0]);
    accr[1] = fmaf(aa0.y, vd, accr[1]);
    accr[2] = fmaf(aa0.z, vd, accr[2]);
    accr[3] = fmaf(aa0.w, vd, accr[3]);
    accr[4] = fmaf(aa1.x, vd, accr[4]);
    accr[5] = fmaf(aa1.y, vd, accr[5]);
    accr[6] = fmaf(aa1.z, vd, accr[6]);
    accr[7] = fmaf(aa1.w, vd, accr[7]);
  }

  // ---- block reduction, then one atomic per output ----
#pragma unroll
  for (int kk = 0; kk < 8; ++kk) accLds[wave][kk][lane] = accr[kk];
#pragma unroll
  for (int kk = 0; kk < 8; ++kk) {
    float c = wredsum(colp[kk]);
    if (lane == kk) colLds[wave][kk] = c;
  }
  __syncthreads();
#pragma unroll
  for (int r = 0; r < 2; ++r) {
    const int o = tid + r * 256;     // 0..511 -> (k,d)
    const int kk = o >> 6, d = o & 63;
    float s = accLds[0][kk][d] + accLds[1][kk][d] + accLds[2][kk][d] + accLds[3][kk][d];
    atomicAdd(&acc[(b * 8 + kk) * 64 + d], s);
  }
  if (tid < 8) {
    float s = colLds[0][tid] + colLds[1][tid] + colLds[2][tid] + colLds[3][tid];
    atomicAdd(&colsum[b * 8 + tid], s);
  }
}

// ---------------------------------------------------------------------------
// K4: updates -> GRU -> LN -> MLP -> residual; also emits next-iter q and
// zeroes acc/colsum. One wave per (b,k) row. grid 128 x 256.
__global__ __launch_bounds__(256) void k_update(
    float* __restrict__ acc, float* __restrict__ colsum,
    float* __restrict__ slots,
    const float* __restrict__ wihT, const float* __restrict__ whhT,
    const float* __restrict__ w1T, const float* __restrict__ w2T,
    const float* __restrict__ wqT,
    const float* __restrict__ b_ih, const float* __restrict__ b_hh,
    const float* __restrict__ mb1, const float* __restrict__ mb2,
    const float* __restrict__ g_ml, const float* __restrict__ b_ml,
    const float* __restrict__ g_sl, const float* __restrict__ b_sl,
    float* __restrict__ q_t, float* __restrict__ dout)
{
  __shared__ float S[4][256];
  const int tid = threadIdx.x, lane = tid & 63, wave = tid >> 6;
  const int row = blockIdx.x * 4 + wave;   // 0..511
  const int b = row >> 3, ks = row & 7;

  const float csum = colsum[row];
  const float u = acc[row * 64 + lane] / csum;
  const float h = slots[row * 64 + lane];
  acc[row * 64 + lane] = 0.f;            // ready for next k_attn
  if (lane == 0) colsum[row] = 0.f;

  float* Su = &S[wave][0];
  float* Sh = &S[wave][64];
  Su[lane] = u; Sh[lane] = h;
  __syncthreads();

  float gir = b_ih[lane], giz = b_ih[64 + lane], gin = b_ih[128 + lane];
  float ghr = b_hh[lane], ghz = b_hh[64 + lane], ghn = b_hh[128 + lane];
#pragma unroll 4
  for (int f = 0; f < 64; ++f) {
    const float uf = Su[f], hf = Sh[f];
    gir = fmaf(uf, wihT[f * 192 + lane], gir);
    giz = fmaf(uf, wihT[f * 192 + 64 + lane], giz);
    gin = fmaf(uf, wihT[f * 192 + 128 + lane], gin);
    ghr = fmaf(hf, whhT[f * 192 + lane], ghr);
    ghz = fmaf(hf, whhT[f * 192 + 64 + lane], ghz);
    ghn = fmaf(hf, whhT[f * 192 + 128 + lane], ghn);
  }
  const float r = 1.f / (1.f + expf(-(gir + ghr)));
  const float z = 1.f / (1.f + expf(-(giz + ghz)));
  const float nn = tanhf(fmaf(r, ghn, gin));
  const float hnew = (1.f - z) * nn + z * h;

  // LN (mlp)
  float mu = wredsum(hnew) * (1.f / 64.f);
  float dx = hnew - mu;
  float var = wredsum(dx * dx) * (1.f / 64.f);
  const float ln = dx * rsqrtf(var + LN_EPS) * g_ml[lane] + b_ml[lane];
  float* Sln = &S[wave][128];
  Sln[lane] = ln;
  __syncthreads();

  float h1a = mb1[lane], h1b = mb1[64 + lane];
#pragma unroll 4
  for (int f = 0; f < 64; ++f) {
    const float lf = Sln[f];
    h1a = fmaf(lf, w1T[f * 128 + lane], h1a);
    h1b = fmaf(lf, w1T[f * 128 + 64 + lane], h1b);
  }
  h1a = fmaxf(h1a, 0.f); h1b = fmaxf(h1b, 0.f);
  __syncthreads();                         // done reading Su/Sh region
  float* Shid = &S[wave][0];
  Shid[lane] = h1a; Shid[64 + lane] = h1b;
  __syncthreads();

  float o = mb2[lane];
#pragma unroll 4
  for (int j = 0; j < 128; ++j) o = fmaf(Shid[j], w2T[j * 64 + lane], o);
  const float snew = hnew + o;
  slots[row * 64 + lane] = snew;
  if (dout) dout[row * 64 + lane] = snew;

  // next-iteration q = LN_slots(snew) @ Wq^T * D^-0.5
  float mu2 = wredsum(snew) * (1.f / 64.f);
  float dx2 = snew - mu2;
  float v2 = wredsum(dx2 * dx2) * (1.f / 64.f);
  const float sq = dx2 * rsqrtf(v2 + LN_EPS) * g_sl[lane] + b_sl[lane];
  __syncthreads();                         // done reading Sln
  float* Ssq = &S[wave][128];
  Ssq[lane] = sq;
  __syncthreads();
  float qe = 0.f;
#pragma unroll 16
  for (int d = 0; d < 64; ++d) qe = fmaf(Ssq[d], wqT[d * 64 + lane], qe);
  q_t[b * 512 + lane * 8 + ks] = qe * 0.125f;
}

// ---------------------------------------------------------------------------
extern "C" void kernel_launch(void* const* d_in, const int* in_sizes, int n_in,
                              void* d_out, int out_size, void* d_ws, size_t ws_size,
                              hipStream_t stream) {
  const float* inp   = (const float*)d_in[0];
  const float* noise = (const float*)d_in[1];
  const float* smu   = (const float*)d_in[2];
  const float* slsig = (const float*)d_in[3];
  const float* Wq    = (const float*)d_in[4];
  const float* Wk    = (const float*)d_in[5];
  const float* Wv    = (const float*)d_in[6];
  const float* w_ih  = (const float*)d_in[7];
  const float* w_hh  = (const float*)d_in[8];
  const float* b_ih  = (const float*)d_in[9];
  const float* b_hh  = (const float*)d_in[10];
  const float* w1    = (const float*)d_in[11];
  const float* b1    = (const float*)d_in[12];
  const float* w2    = (const float*)d_in[13];
  const float* b2    = (const float*)d_in[14];
  const float* g_in  = (const float*)d_in[15];
  const float* bi_in = (const float*)d_in[16];
  const float* g_sl  = (const float*)d_in[17];
  const float* bi_sl = (const float*)d_in[18];
  const float* g_ml  = (const float*)d_in[19];
  const float* bi_ml = (const float*)d_in[20];

  float* ws   = (float*)d_ws;
  float* kt   = ws + OFF_KT;
  float* vv   = ws + OFF_V;
  float* qt   = ws + OFF_QT;
  float* ac   = ws + OFF_ACC;
  float* cs   = ws + OFF_COL;
  float* sl   = ws + OFF_SLOTS;
  float* wihT = ws + OFF_WIHT;
  float* whhT = ws + OFF_WHHT;
  float* w1T  = ws + OFF_W1T;
  float* w2T  = ws + OFF_W2T;
  float* wqT  = ws + OFF_WQT;
  float* wkv  = ws + OFF_WKV;

  k_prep<<<208, 256, 0, stream>>>(w_ih, w_hh, w1, w2, Wq, Wk, Wv,
                                  wihT, whhT, w1T, w2T, wqT, wkv);
  k_ln_project<<<4096, 256, 0, stream>>>(inp, wkv, g_in, bi_in, kt, vv);
  k_init<<<128, 256, 0, stream>>>(noise, smu, slsig, wqT, g_sl, bi_sl, sl, qt, ac, cs);
  for (int it = 0; it < 3; ++it) {
    k_attn<<<1024, 256, 0, stream>>>(kt, vv, qt, ac, cs);
    k_update<<<128, 256, 0, stream>>>(ac, cs, sl, wihT, whhT, w1T, w2T, wqT,
                                      b_ih, b_hh, b1, b2, g_ml, bi_ml, g_sl, bi_sl,
                                      qt, it == 2 ? (float*)d_out : nullptr);
  }
}

// Round 3
// 308.305 us; speedup vs baseline: 2.0862x; 1.1337x over previous
//
#include <hip/hip_runtime.h>
#include <math.h>

#define BB 64
#define NN 4096
#define KS 8
#define DD 64
#define LN_EPS 1e-5f
#define EPS 1e-8f

typedef unsigned short ushortT;
typedef unsigned int uintT;
typedef __attribute__((ext_vector_type(8))) short short8;
typedef __attribute__((ext_vector_type(4))) float f32x4;
typedef __attribute__((ext_vector_type(4))) unsigned short us4;
typedef __attribute__((ext_vector_type(4))) unsigned int u32x4;

// workspace offsets (in floats)
#define OFF_KT    0L          // kt2: bf16x2 pairs [b][d2=32][n]  8388608 uints
#define OFF_V     16777216L   // vv2: bf16x2 pairs [b][n2=2048][d] 8388608 uints
#define OFF_QT    33554432L   // q  [b][d][k], pre-scaled  32768
#define OFF_ACC   33587200L   // acc [b][k][d]             32768
#define OFF_COL   33619968L   // colsum [b][k]             512
#define OFF_SLOTS 33620480L   // slots [b][k][d]           32768
#define OFF_WIHT  33653248L   // w_ih^T [64][192]          12288
#define OFF_WHHT  33665536L   // w_hh^T [64][192]          12288
#define OFF_W1T   33677824L   // mlp_w1^T [64][128]        8192
#define OFF_W2T   33686016L   // mlp_w2^T [128][64]        8192
#define OFF_WQT   33694208L   // Wq^T [64][64]             4096
#define OFF_WKV   33698304L   // wpack bf16 MFMA B-frags   8192 ushorts (16KB)

__device__ __forceinline__ float wredsum(float v) {
#pragma unroll
  for (int off = 32; off > 0; off >>= 1) v += __shfl_xor(v, off);
  return v;
}

__device__ __forceinline__ ushortT f2bf(float f) {
  uintT b = __float_as_uint(f);
  b += 0x7fff + ((b >> 16) & 1);          // RNE
  return (ushortT)(b >> 16);
}

// ---------------------------------------------------------------------------
// K0: weight prep. fp32 transposes for update/init kernels + bf16 MFMA
// B-fragment packing for the projection. 53248 elements, grid 208 x 256.
// wpack layout: frag (ct 0..7, kb 0..1), lane l, j0..7:
//   element B[k = kb*32 + (l>>4)*8 + j][col = ct*16 + (l&15)],
//   B[f][col] = Wk[col][f] (col<64) else Wv[col-64][f].
__global__ __launch_bounds__(256) void k_prep(
    const float* __restrict__ w_ih, const float* __restrict__ w_hh,
    const float* __restrict__ w1, const float* __restrict__ w2,
    const float* __restrict__ Wq,
    const float* __restrict__ Wk, const float* __restrict__ Wv,
    float* __restrict__ wihT, float* __restrict__ whhT,
    float* __restrict__ w1T, float* __restrict__ w2T, float* __restrict__ wqT,
    ushortT* __restrict__ wpack)
{
  int idx = blockIdx.x * 256 + threadIdx.x;
  if (idx < 12288) {
    int j = idx >> 6, f = idx & 63;
    wihT[f * 192 + j] = w_ih[idx];
  } else if (idx < 24576) {
    int i = idx - 12288; int j = i >> 6, f = i & 63;
    whhT[f * 192 + j] = w_hh[i];
  } else if (idx < 32768) {
    int i = idx - 24576; int j = i >> 6, f = i & 63;
    w1T[f * 128 + j] = w1[i];
  } else if (idx < 40960) {
    int i = idx - 32768; int d = i >> 7, j = i & 127;
    w2T[j * 64 + d] = w2[i];
  } else if (idx < 45056) {
    int i = idx - 40960; int e = i >> 6, d = i & 63;
    wqT[d * 64 + e] = Wq[i];
  } else if (idx < 53248) {
    int i = idx - 45056;                 // 0..8191
    int j = i & 7, l = (i >> 3) & 63, t2 = i >> 9;
    int ct = t2 >> 1, kb = t2 & 1;
    int kf = kb * 32 + ((l >> 4) << 3) + j;
    int col = (ct << 4) | (l & 15);
    float val = (col < 64) ? Wk[col * 64 + kf] : Wv[(col - 64) * 64 + kf];
    wpack[i] = f2bf(val);
  }
}

// ---------------------------------------------------------------------------
// K1: fused LayerNorm + K/V projection via bf16 MFMA.
// block = 256 (4 waves), tile = 64 tokens; grid = 4096.
// Stage 1 (lane=f): LN fp32, xn -> LDS bf16 [64 tok][72].
// Stage 2: wave w owns output cols [32w, 32w+32) of the 128 (k|v) cols.
//   16 x mfma_f32_16x16x32_bf16; B-frags preloaded coalesced from wpack.
// Epilogue: C tiles -> LDS (k in [col][tok] for packed b64 writes, v in
//   [tok][col]) -> packed bf16x2 global stores (kt2 pairs d, vv2 pairs n).
__global__ __launch_bounds__(256) void k_ln_project(
    const float* __restrict__ inp, const ushortT* __restrict__ wpack,
    const float* __restrict__ g, const float* __restrict__ bbv,
    uintT* __restrict__ kt2, uintT* __restrict__ vv2)
{
  __shared__ __align__(16) ushortT xn[64 * 72];
  __shared__ __align__(16) ushortT kstageT[64 * 68];   // [col d][token]
  __shared__ __align__(16) ushortT vstage[64 * 68];    // [token][col d]
  const int tid = threadIdx.x;
  const int lane = tid & 63;
  const int wave = tid >> 6;
  const int tile = blockIdx.x;        // 0..4095
  const int b = tile >> 6;
  const int n0 = (tile & 63) << 6;
  const float* rowbase = inp + (((long)b * NN + n0) << 6);
  const float gg = g[lane];
  const float bv = bbv[lane];

  // stage 1: LN 16 rows per wave, lane = feature
  for (int r = 0; r < 16; ++r) {
    const int lrow = wave * 16 + r;
    float x = rowbase[lrow * 64 + lane];
    float mu = wredsum(x) * (1.f / 64.f);
    float dx = x - mu;
    float var = wredsum(dx * dx) * (1.f / 64.f);
    xn[lrow * 72 + lane] = f2bf(dx * rsqrtf(var + LN_EPS) * gg + bv);
  }

  // B fragments (no LDS dep: issue before barrier)
  short8 bfrag[2][2];
#pragma unroll
  for (int nt = 0; nt < 2; ++nt)
#pragma unroll
    for (int kb = 0; kb < 2; ++kb)
      bfrag[nt][kb] = *(const short8*)&wpack[((((2 * wave + nt) << 1) | kb) * 64 + lane) << 3];

  __syncthreads();

  const int l15 = lane & 15, q = lane >> 4;
  f32x4 acc[4][2];
#pragma unroll
  for (int mt = 0; mt < 4; ++mt)
#pragma unroll
    for (int nt = 0; nt < 2; ++nt) acc[mt][nt] = (f32x4){0.f, 0.f, 0.f, 0.f};

#pragma unroll
  for (int mt = 0; mt < 4; ++mt) {
    const ushortT* abase = &xn[(mt * 16 + l15) * 72 + q * 8];
    short8 a0 = *(const short8*)abase;
    short8 a1 = *(const short8*)(abase + 32);
#pragma unroll
    for (int nt = 0; nt < 2; ++nt) {
      acc[mt][nt] = __builtin_amdgcn_mfma_f32_16x16x32_bf16(a0, bfrag[nt][0], acc[mt][nt], 0, 0, 0);
      acc[mt][nt] = __builtin_amdgcn_mfma_f32_16x16x32_bf16(a1, bfrag[nt][1], acc[mt][nt], 0, 0, 0);
    }
  }

  // C layout: token m = mt*16 + q*4 + r, col = (2*wave+nt)*16 + l15
  if (wave < 2) {
#pragma unroll
    for (int mt = 0; mt < 4; ++mt)
#pragma unroll
      for (int nt = 0; nt < 2; ++nt) {
        const int col = (2 * wave + nt) * 16 + l15;
        us4 p = {f2bf(acc[mt][nt].x), f2bf(acc[mt][nt].y),
                 f2bf(acc[mt][nt].z), f2bf(acc[mt][nt].w)};
        *(us4*)&kstageT[col * 68 + mt * 16 + q * 4] = p;
      }
  } else {
#pragma unroll
    for (int mt = 0; mt < 4; ++mt)
#pragma unroll
      for (int nt = 0; nt < 2; ++nt) {
        const int vcol = (2 * (wave - 2) + nt) * 16 + l15;
        const int m0 = mt * 16 + q * 4;
        vstage[(m0 + 0) * 68 + vcol] = f2bf(acc[mt][nt].x);
        vstage[(m0 + 1) * 68 + vcol] = f2bf(acc[mt][nt].y);
        vstage[(m0 + 2) * 68 + vcol] = f2bf(acc[mt][nt].z);
        vstage[(m0 + 3) * 68 + vcol] = f2bf(acc[mt][nt].w);
      }
  }
  __syncthreads();

  // global writes: pack bf16 pairs into uints, 16B stores
  {
    const int d2 = tid >> 3, nc = (tid & 7) << 3;
    const ushortT* r0 = &kstageT[(2 * d2) * 68 + nc];
    const ushortT* r1 = &kstageT[(2 * d2 + 1) * 68 + nc];
    uintT o[8];
#pragma unroll
    for (int i = 0; i < 8; ++i) o[i] = (uintT)r0[i] | ((uintT)r1[i] << 16);
    uintT* dst = kt2 + ((long)(b * 32 + d2)) * NN + n0 + nc;
    *(u32x4*)dst = (u32x4){o[0], o[1], o[2], o[3]};
    *(u32x4*)(dst + 4) = (u32x4){o[4], o[5], o[6], o[7]};
  }
  {
    const int n2 = tid >> 3, cc = (tid & 7) << 3;
    const ushortT* r0 = &vstage[(2 * n2) * 68 + cc];
    const ushortT* r1 = &vstage[(2 * n2 + 1) * 68 + cc];
    uintT o[8];
#pragma unroll
    for (int i = 0; i < 8; ++i) o[i] = (uintT)r0[i] | ((uintT)r1[i] << 16);
    uintT* dst = vv2 + ((long)b * 2048 + (n0 >> 1) + n2) * 64 + cc;
    *(u32x4*)dst = (u32x4){o[0], o[1], o[2], o[3]};
    *(u32x4*)(dst + 4) = (u32x4){o[4], o[5], o[6], o[7]};
  }
}

// ---------------------------------------------------------------------------
// K2: slots init + LN + q0 (+ zero acc/colsum). One wave per (b,k) row.
__global__ __launch_bounds__(256) void k_init(
    const float* __restrict__ noise, const float* __restrict__ smu,
    const float* __restrict__ slsig, const float* __restrict__ wqT,
    const float* __restrict__ g_sl, const float* __restrict__ b_sl,
    float* __restrict__ slots, float* __restrict__ q_t,
    float* __restrict__ acc, float* __restrict__ colsum)
{
  __shared__ float S[4][64];
  const int tid = threadIdx.x, lane = tid & 63, wave = tid >> 6;
  const int row = blockIdx.x * 4 + wave;   // 0..511
  const int b = row >> 3, ks = row & 7;

  float s0 = fmaf(expf(slsig[lane]), noise[row * 64 + lane], smu[lane]);
  slots[row * 64 + lane] = s0;
  acc[row * 64 + lane] = 0.f;
  if (lane == 0) colsum[row] = 0.f;

  float mu = wredsum(s0) * (1.f / 64.f);
  float dx = s0 - mu;
  float var = wredsum(dx * dx) * (1.f / 64.f);
  float sn = dx * rsqrtf(var + LN_EPS) * g_sl[lane] + b_sl[lane];
  S[wave][lane] = sn;
  __syncthreads();
  float qe = 0.f;
#pragma unroll 16
  for (int d = 0; d < 64; ++d) qe = fmaf(S[wave][d], wqT[d * 64 + lane], qe);
  q_t[b * 512 + lane * 8 + ks] = qe * 0.125f;   // pre-scaled, layout [b][d][k]
}

// ---------------------------------------------------------------------------
// K3: fused attention pass, bf16x2-packed streams. One 64-n chunk per wave.
// Phase A (lane=n): 32 packed k loads -> logits (q via scalar loads),
//   softmax over K=8 -> attn LDS. Phase B (lane=d): 32 packed v loads,
//   acc[k][d] += attn*v. Block LDS reduction -> 1 atomic per output.
// grid 1024 x 256.
__global__ __launch_bounds__(256) void k_attn(
    const uintT* __restrict__ kt2, const uintT* __restrict__ vv2,
    const float* __restrict__ q_t,
    float* __restrict__ acc, float* __restrict__ colsum)
{
  __shared__ float attnLds[4][64 * 8];
  __shared__ float accLds[4][8][64];
  __shared__ float colLds[4][8];
  const int tid = threadIdx.x;
  const int lane = tid & 63;
  const int wave = tid >> 6;
  const int b = blockIdx.x >> 4;
  const int chunk = ((blockIdx.x & 15) << 2) | wave;  // 0..63
  const int n0 = chunk << 6;
  const float* qb = q_t + b * 512;   // uniform -> scalar loads

  // ---- Phase A ----
  float logit[8];
#pragma unroll
  for (int i = 0; i < 8; ++i) logit[i] = 0.f;
  const uintT* kb2 = kt2 + (long)b * (32L * NN) + n0 + lane;
#pragma unroll
  for (int d2 = 0; d2 < 32; ++d2) {
    uintT u = kb2[d2 * NN];
    float klo = __uint_as_float(u << 16);            // d = 2*d2
    float khi = __uint_as_float(u & 0xffff0000u);    // d = 2*d2+1
#pragma unroll
    for (int kk = 0; kk < 8; ++kk) {
      logit[kk] = fmaf(klo, qb[(2 * d2) * 8 + kk], logit[kk]);
      logit[kk] = fmaf(khi, qb[(2 * d2 + 1) * 8 + kk], logit[kk]);
    }
  }
  float m = logit[0];
#pragma unroll
  for (int kk = 1; kk < 8; ++kk) m = fmaxf(m, logit[kk]);
  float e[8]; float ssum = 0.f;
#pragma unroll
  for (int kk = 0; kk < 8; ++kk) { e[kk] = __expf(logit[kk] - m); ssum += e[kk]; }
  float inv = 1.f / ssum;
  float4 a0, a1;
  a0.x = fmaf(e[0], inv, EPS); a0.y = fmaf(e[1], inv, EPS);
  a0.z = fmaf(e[2], inv, EPS); a0.w = fmaf(e[3], inv, EPS);
  a1.x = fmaf(e[4], inv, EPS); a1.y = fmaf(e[5], inv, EPS);
  a1.z = fmaf(e[6], inv, EPS); a1.w = fmaf(e[7], inv, EPS);
  float colp[8];
  colp[0] = a0.x; colp[1] = a0.y; colp[2] = a0.z; colp[3] = a0.w;
  colp[4] = a1.x; colp[5] = a1.y; colp[6] = a1.z; colp[7] = a1.w;
  ((float4*)&attnLds[wave][lane * 8])[0] = a0;
  ((float4*)&attnLds[wave][lane * 8])[1] = a1;
  __syncthreads();

  // ---- Phase B ----
  float accr[8];
#pragma unroll
  for (int i = 0; i < 8; ++i) accr[i] = 0.f;
  const uintT* vb2 = vv2 + ((long)b * 2048 + (n0 >> 1)) * 64 + lane;
#pragma unroll 4
  for (int n2 = 0; n2 < 32; ++n2) {
    uintT u = vb2[n2 * 64];
    float vlo = __uint_as_float(u << 16);            // n = 2*n2
    float vhi = __uint_as_float(u & 0xffff0000u);    // n = 2*n2+1
    const float4 aa0 = ((const float4*)&attnLds[wave][(2 * n2) * 8])[0];
    const float4 aa1 = ((const float4*)&attnLds[wave][(2 * n2) * 8])[1];
    const float4 bb0 = ((const float4*)&attnLds[wave][(2 * n2 + 1) * 8])[0];
    const float4 bb1 = ((const float4*)&attnLds[wave][(2 * n2 + 1) * 8])[1];
    accr[0] = fmaf(aa0.x, vlo, fmaf(bb0.x, vhi, accr[0]));
    accr[1] = fmaf(aa0.y, vlo, fmaf(bb0.y, vhi, accr[1]));
    accr[2] = fmaf(aa0.z, vlo, fmaf(bb0.z, vhi, accr[2]));
    accr[3] = fmaf(aa0.w, vlo, fmaf(bb0.w, vhi, accr[3]));
    accr[4] = fmaf(aa1.x, vlo, fmaf(bb1.x, vhi, accr[4]));
    accr[5] = fmaf(aa1.y, vlo, fmaf(bb1.y, vhi, accr[5]));
    accr[6] = fmaf(aa1.z, vlo, fmaf(bb1.z, vhi, accr[6]));
    accr[7] = fmaf(aa1.w, vlo, fmaf(bb1.w, vhi, accr[7]));
  }

  // ---- block reduction, then one atomic per output ----
#pragma unroll
  for (int kk = 0; kk < 8; ++kk) accLds[wave][kk][lane] = accr[kk];
#pragma unroll
  for (int kk = 0; kk < 8; ++kk) {
    float c = wredsum(colp[kk]);
    if (lane == kk) colLds[wave][kk] = c;
  }
  __syncthreads();
#pragma unroll
  for (int r = 0; r < 2; ++r) {
    const int o = tid + r * 256;     // 0..511 -> (k,d)
    const int kk = o >> 6, d = o & 63;
    float s = accLds[0][kk][d] + accLds[1][kk][d] + accLds[2][kk][d] + accLds[3][kk][d];
    atomicAdd(&acc[(b * 8 + kk) * 64 + d], s);
  }
  if (tid < 8) {
    float s = colLds[0][tid] + colLds[1][tid] + colLds[2][tid] + colLds[3][tid];
    atomicAdd(&colsum[b * 8 + tid], s);
  }
}

// ---------------------------------------------------------------------------
// K4: updates -> GRU -> LN -> MLP -> residual; emits next-iter q; zeroes
// acc/colsum. One wave per (b,k) row. grid 128 x 256.
__global__ __launch_bounds__(256) void k_update(
    float* __restrict__ acc, float* __restrict__ colsum,
    float* __restrict__ slots,
    const float* __restrict__ wihT, const float* __restrict__ whhT,
    const float* __restrict__ w1T, const float* __restrict__ w2T,
    const float* __restrict__ wqT,
    const float* __restrict__ b_ih, const float* __restrict__ b_hh,
    const float* __restrict__ mb1, const float* __restrict__ mb2,
    const float* __restrict__ g_ml, const float* __restrict__ b_ml,
    const float* __restrict__ g_sl, const float* __restrict__ b_sl,
    float* __restrict__ q_t, float* __restrict__ dout)
{
  __shared__ float S[4][256];
  const int tid = threadIdx.x, lane = tid & 63, wave = tid >> 6;
  const int row = blockIdx.x * 4 + wave;   // 0..511
  const int b = row >> 3, ks = row & 7;

  const float csum = colsum[row];
  const float u = acc[row * 64 + lane] / csum;
  const float h = slots[row * 64 + lane];
  acc[row * 64 + lane] = 0.f;            // ready for next k_attn
  if (lane == 0) colsum[row] = 0.f;

  float* Su = &S[wave][0];
  float* Sh = &S[wave][64];
  Su[lane] = u; Sh[lane] = h;
  __syncthreads();

  float gir = b_ih[lane], giz = b_ih[64 + lane], gin = b_ih[128 + lane];
  float ghr = b_hh[lane], ghz = b_hh[64 + lane], ghn = b_hh[128 + lane];
#pragma unroll 4
  for (int f = 0; f < 64; ++f) {
    const float uf = Su[f], hf = Sh[f];
    gir = fmaf(uf, wihT[f * 192 + lane], gir);
    giz = fmaf(uf, wihT[f * 192 + 64 + lane], giz);
    gin = fmaf(uf, wihT[f * 192 + 128 + lane], gin);
    ghr = fmaf(hf, whhT[f * 192 + lane], ghr);
    ghz = fmaf(hf, whhT[f * 192 + 64 + lane], ghz);
    ghn = fmaf(hf, whhT[f * 192 + 128 + lane], ghn);
  }
  const float r = 1.f / (1.f + expf(-(gir + ghr)));
  const float z = 1.f / (1.f + expf(-(giz + ghz)));
  const float nn = tanhf(fmaf(r, ghn, gin));
  const float hnew = (1.f - z) * nn + z * h;

  // LN (mlp)
  float mu = wredsum(hnew) * (1.f / 64.f);
  float dx = hnew - mu;
  float var = wredsum(dx * dx) * (1.f / 64.f);
  const float ln = dx * rsqrtf(var + LN_EPS) * g_ml[lane] + b_ml[lane];
  float* Sln = &S[wave][128];
  Sln[lane] = ln;
  __syncthreads();

  float h1a = mb1[lane], h1b = mb1[64 + lane];
#pragma unroll 4
  for (int f = 0; f < 64; ++f) {
    const float lf = Sln[f];
    h1a = fmaf(lf, w1T[f * 128 + lane], h1a);
    h1b = fmaf(lf, w1T[f * 128 + 64 + lane], h1b);
  }
  h1a = fmaxf(h1a, 0.f); h1b = fmaxf(h1b, 0.f);
  __syncthreads();                         // done reading Su/Sh region
  float* Shid = &S[wave][0];
  Shid[lane] = h1a; Shid[64 + lane] = h1b;
  __syncthreads();

  float o = mb2[lane];
#pragma unroll 4
  for (int j = 0; j < 128; ++j) o = fmaf(Shid[j], w2T[j * 64 + lane], o);
  const float snew = hnew + o;
  slots[row * 64 + lane] = snew;
  if (dout) dout[row * 64 + lane] = snew;

  // next-iteration q = LN_slots(snew) @ Wq^T * D^-0.5
  float mu2 = wredsum(snew) * (1.f / 64.f);
  float dx2 = snew - mu2;
  float v2 = wredsum(dx2 * dx2) * (1.f / 64.f);
  const float sq = dx2 * rsqrtf(v2 + LN_EPS) * g_sl[lane] + b_sl[lane];
  __syncthreads();                         // done reading Sln
  float* Ssq = &S[wave][128];
  Ssq[lane] = sq;
  __syncthreads();
  float qe = 0.f;
#pragma unroll 16
  for (int d = 0; d < 64; ++d) qe = fmaf(Ssq[d], wqT[d * 64 + lane], qe);
  q_t[b * 512 + lane * 8 + ks] = qe * 0.125f;
}

// ---------------------------------------------------------------------------
extern "C" void kernel_launch(void* const* d_in, const int* in_sizes, int n_in,
                              void* d_out, int out_size, void* d_ws, size_t ws_size,
                              hipStream_t stream) {
  const float* inp   = (const float*)d_in[0];
  const float* noise = (const float*)d_in[1];
  const float* smu   = (const float*)d_in[2];
  const float* slsig = (const float*)d_in[3];
  const float* Wq    = (const float*)d_in[4];
  const float* Wk    = (const float*)d_in[5];
  const float* Wv    = (const float*)d_in[6];
  const float* w_ih  = (const float*)d_in[7];
  const float* w_hh  = (const float*)d_in[8];
  const float* b_ih  = (const float*)d_in[9];
  const float* b_hh  = (const float*)d_in[10];
  const float* w1    = (const float*)d_in[11];
  const float* b1    = (const float*)d_in[12];
  const float* w2    = (const float*)d_in[13];
  const float* b2    = (const float*)d_in[14];
  const float* g_in  = (const float*)d_in[15];
  const float* bi_in = (const float*)d_in[16];
  const float* g_sl  = (const float*)d_in[17];
  const float* bi_sl = (const float*)d_in[18];
  const float* g_ml  = (const float*)d_in[19];
  const float* bi_ml = (const float*)d_in[20];

  float* ws     = (float*)d_ws;
  uintT* kt2    = (uintT*)(ws + OFF_KT);
  uintT* vv2    = (uintT*)(ws + OFF_V);
  float* qt     = ws + OFF_QT;
  float* ac     = ws + OFF_ACC;
  float* cs     = ws + OFF_COL;
  float* sl     = ws + OFF_SLOTS;
  float* wihT   = ws + OFF_WIHT;
  float* whhT   = ws + OFF_WHHT;
  float* w1T    = ws + OFF_W1T;
  float* w2T    = ws + OFF_W2T;
  float* wqT    = ws + OFF_WQT;
  ushortT* wpk  = (ushortT*)(ws + OFF_WKV);

  k_prep<<<208, 256, 0, stream>>>(w_ih, w_hh, w1, w2, Wq, Wk, Wv,
                                  wihT, whhT, w1T, w2T, wqT, wpk);
  k_ln_project<<<4096, 256, 0, stream>>>(inp, wpk, g_in, bi_in, kt2, vv2);
  k_init<<<128, 256, 0, stream>>>(noise, smu, slsig, wqT, g_sl, bi_sl, sl, qt, ac, cs);
  for (int it = 0; it < 3; ++it) {
    k_attn<<<1024, 256, 0, stream>>>(kt2, vv2, qt, ac, cs);
    k_update<<<128, 256, 0, stream>>>(ac, cs, sl, wihT, whhT, w1T, w2T, wqT,
                                      b_ih, b_hh, b1, b2, g_ml, bi_ml, g_sl, bi_sl,
                                      qt, it == 2 ? (float*)d_out : nullptr);
  }
}

// Round 4
// 246.443 us; speedup vs baseline: 2.6099x; 1.2510x over previous
//
#include <hip/hip_runtime.h>
#include <math.h>

#define NN 4096
#define LN_EPS 1e-5f
#define EPS 1e-8f

typedef unsigned short ushortT;
typedef unsigned int uintT;
typedef __attribute__((ext_vector_type(8))) short short8;
typedef __attribute__((ext_vector_type(4))) float f32x4;
typedef __attribute__((ext_vector_type(4))) unsigned short us4;

// workspace offsets (in floats)
// ktF: bf16 A-frags  [b][c=64][frag=8][lane=64][j=8] = 16.78M ushorts (32 MB)
// vF : bf16 B-frags  same shape
// qF : bf16 B-frags  [b][kb=2][lane=64][j=8] = 65536 ushorts (128 KB)
#define OFF_KT    0L
#define OFF_V     16777216L
#define OFF_QT    33554432L
#define OFF_ACC   33587200L   // acc [b][k][d] f32          32768
#define OFF_COL   33619968L   // colsum [b][k] f32          512
#define OFF_SLOTS 33620480L   // slots [b][k][d] f32        32768
#define OFF_WIHT  33653248L   // w_ih^T [64][192]           12288
#define OFF_WHHT  33665536L   // w_hh^T [64][192]           12288
#define OFF_W1T   33677824L   // mlp_w1^T [64][128]         8192
#define OFF_W2T   33686016L   // mlp_w2^T [128][64]         8192
#define OFF_WQT   33694208L   // Wq^T [64][64]              4096
#define OFF_WKV   33698304L   // wpack bf16 MFMA B-frags    8192 ushorts

__device__ __forceinline__ float wredsum(float v) {
#pragma unroll
  for (int off = 32; off > 0; off >>= 1) v += __shfl_xor(v, off);
  return v;
}

__device__ __forceinline__ ushortT f2bf(float f) {
  uintT b = __float_as_uint(f);
  b += 0x7fff + ((b >> 16) & 1);          // RNE
  return (ushortT)(b >> 16);
}

// ---------------------------------------------------------------------------
// K0: weight prep (unchanged from R3). wpack: B-frags for LN-projection GEMM.
__global__ __launch_bounds__(256) void k_prep(
    const float* __restrict__ w_ih, const float* __restrict__ w_hh,
    const float* __restrict__ w1, const float* __restrict__ w2,
    const float* __restrict__ Wq,
    const float* __restrict__ Wk, const float* __restrict__ Wv,
    float* __restrict__ wihT, float* __restrict__ whhT,
    float* __restrict__ w1T, float* __restrict__ w2T, float* __restrict__ wqT,
    ushortT* __restrict__ wpack)
{
  int idx = blockIdx.x * 256 + threadIdx.x;
  if (idx < 12288) {
    int j = idx >> 6, f = idx & 63;
    wihT[f * 192 + j] = w_ih[idx];
  } else if (idx < 24576) {
    int i = idx - 12288; int j = i >> 6, f = i & 63;
    whhT[f * 192 + j] = w_hh[i];
  } else if (idx < 32768) {
    int i = idx - 24576; int j = i >> 6, f = i & 63;
    w1T[f * 128 + j] = w1[i];
  } else if (idx < 40960) {
    int i = idx - 32768; int d = i >> 7, j = i & 127;
    w2T[j * 64 + d] = w2[i];
  } else if (idx < 45056) {
    int i = idx - 40960; int e = i >> 6, d = i & 63;
    wqT[d * 64 + e] = Wq[i];
  } else if (idx < 53248) {
    int i = idx - 45056;                 // 0..8191
    int j = i & 7, l = (i >> 3) & 63, t2 = i >> 9;
    int ct = t2 >> 1, kb = t2 & 1;
    int kf = kb * 32 + ((l >> 4) << 3) + j;
    int col = (ct << 4) | (l & 15);
    float val = (col < 64) ? Wk[col * 64 + kf] : Wv[(col - 64) * 64 + kf];
    wpack[i] = f2bf(val);
  }
}

// ---------------------------------------------------------------------------
// K1: fused LayerNorm + K/V projection via bf16 MFMA, fragment-order output.
// block = 256 (4 waves), tile = 64 tokens (== one attn chunk); grid = 4096.
// Stage 1: 4 rows/pass, lane=(q=row-in-4, l15=col4); 8 shuffles per pass.
//   xn written straight into MFMA A-fragment order (conflict-light).
// Stage 2: 16 MFMAs. Epilogue: v C-regs -> global vF B-frags directly
//   (coalesced 512B blocks); k C-regs -> LDS frag stage -> linear copy.
__global__ __launch_bounds__(256) void k_ln_project(
    const float* __restrict__ inp, const ushortT* __restrict__ wpack,
    const float* __restrict__ g, const float* __restrict__ bbv,
    ushortT* __restrict__ ktF, ushortT* __restrict__ vF)
{
  __shared__ __align__(16) ushortT xnF[4096];   // [frag8][lane64][j8]
  __shared__ __align__(16) ushortT kS[4096];    // k frags staging
  const int tid = threadIdx.x;
  const int lane = tid & 63;
  const int wave = tid >> 6;
  const int l15 = lane & 15, q = lane >> 4;
  const int tile = blockIdx.x;
  const int b = tile >> 6;
  const int c = tile & 63;
  const int n0 = c << 6;
  const float* rowbase = inp + (((long)b * NN + n0) << 6);
  const float4 g4 = *(const float4*)&g[l15 << 2];
  const float4 b4 = *(const float4*)&bbv[l15 << 2];

  // stage 1: LN, 4 rows per pass (row = wave*16 + i*4 + q, lane holds 4 cols)
#pragma unroll
  for (int i = 0; i < 4; ++i) {
    const int row = (wave << 4) + (i << 2) + q;
    float4 x = *(const float4*)&rowbase[(row << 6) + (l15 << 2)];
    float s = x.x + x.y + x.z + x.w;
    s += __shfl_xor(s, 1); s += __shfl_xor(s, 2);
    s += __shfl_xor(s, 4); s += __shfl_xor(s, 8);
    const float mu = s * (1.f / 64.f);
    float4 dx = {x.x - mu, x.y - mu, x.z - mu, x.w - mu};
    float ss = dx.x * dx.x + dx.y * dx.y + dx.z * dx.z + dx.w * dx.w;
    ss += __shfl_xor(ss, 1); ss += __shfl_xor(ss, 2);
    ss += __shfl_xor(ss, 4); ss += __shfl_xor(ss, 8);
    const float rs = rsqrtf(ss * (1.f / 64.f) + LN_EPS);
    us4 p = {f2bf(dx.x * rs * g4.x + b4.x), f2bf(dx.y * rs * g4.y + b4.y),
             f2bf(dx.z * rs * g4.z + b4.z), f2bf(dx.w * rs * g4.w + b4.w)};
    // fragment coords: n=row, d=l15*4..+3 -> frag=wave*2+(l15>>3),
    // lane'=((l15&7)>>1)*16+(row&15), j0=(l15&1)*4
    *(us4*)&xnF[((((wave << 1) + (l15 >> 3)) << 6) + (((l15 & 7) >> 1) << 4)
                 + (row & 15)) * 8 + ((l15 & 1) << 2)] = p;
  }

  // B frags (no LDS dep)
  short8 bfrag[2][2];
#pragma unroll
  for (int nt = 0; nt < 2; ++nt)
#pragma unroll
    for (int kb = 0; kb < 2; ++kb)
      bfrag[nt][kb] = *(const short8*)&wpack[((((2 * wave + nt) << 1) | kb) * 64 + lane) << 3];

  __syncthreads();

  f32x4 acc[4][2];
#pragma unroll
  for (int mt = 0; mt < 4; ++mt)
#pragma unroll
    for (int nt = 0; nt < 2; ++nt) acc[mt][nt] = (f32x4){0.f, 0.f, 0.f, 0.f};

#pragma unroll
  for (int mt = 0; mt < 4; ++mt) {
    short8 a0 = *(const short8*)&xnF[((mt * 2 + 0) * 64 + lane) << 3];
    short8 a1 = *(const short8*)&xnF[((mt * 2 + 1) * 64 + lane) << 3];
#pragma unroll
    for (int nt = 0; nt < 2; ++nt) {
      acc[mt][nt] = __builtin_amdgcn_mfma_f32_16x16x32_bf16(a0, bfrag[nt][0], acc[mt][nt], 0, 0, 0);
      acc[mt][nt] = __builtin_amdgcn_mfma_f32_16x16x32_bf16(a1, bfrag[nt][1], acc[mt][nt], 0, 0, 0);
    }
  }

  // epilogue. C: token n = mt*16 + q*4 + r, out-col = (2*wave+nt)*16 + l15
  if (wave < 2) {
    // k cols (d = col). dest frag = mt*2+wave, lane' = (2nt+(l15>>3))*16+q*4+r, j = l15&7
#pragma unroll
    for (int mt = 0; mt < 4; ++mt)
#pragma unroll
      for (int nt = 0; nt < 2; ++nt) {
        const int base = (((mt * 2 + wave) << 6) + ((2 * nt + (l15 >> 3)) << 4) + (q << 2));
#pragma unroll
        for (int r = 0; r < 4; ++r)
          kS[((base + r) << 3) + (l15 & 7)] = f2bf(acc[mt][nt][r]);
      }
  } else {
    // v cols -> global B-frags directly: frag = ntg*2 + (mt>>1),
    // lane' = ((mt&1)*2+(q>>1))*16 + l15, j0 = (q&1)*4 (+r)
    ushortT* vbase = vF + ((long)(b * 64 + c) << 12);
#pragma unroll
    for (int mt = 0; mt < 4; ++mt)
#pragma unroll
      for (int nt = 0; nt < 2; ++nt) {
        const int ntg = 2 * (wave - 2) + nt;
        us4 p = {f2bf(acc[mt][nt][0]), f2bf(acc[mt][nt][1]),
                 f2bf(acc[mt][nt][2]), f2bf(acc[mt][nt][3])};
        *(us4*)&vbase[(((((ntg << 1) + (mt >> 1)) << 6)
                        + (((mt & 1) * 2 + (q >> 1)) << 4) + l15) << 3)
                      + ((q & 1) << 2)] = p;
      }
  }
  __syncthreads();

  // linear copy of k frags to global (coalesced b128)
  ushortT* kdst = ktF + ((long)(b * 64 + c) << 12);
  short8 v0 = *(const short8*)&kS[tid << 4];
  short8 v1 = *(const short8*)&kS[(tid << 4) + 8];
  *(short8*)&kdst[tid << 4] = v0;
  *(short8*)&kdst[(tid << 4) + 8] = v1;
}

// ---------------------------------------------------------------------------
// K2: slots init + LN + q0 as bf16 B-frag (+ zero cols 8..15, zero acc/colsum).
// One wave per (b,k) row. grid 128 x 256.
__global__ __launch_bounds__(256) void k_init(
    const float* __restrict__ noise, const float* __restrict__ smu,
    const float* __restrict__ slsig, const float* __restrict__ wqT,
    const float* __restrict__ g_sl, const float* __restrict__ b_sl,
    float* __restrict__ slots, ushortT* __restrict__ qF,
    float* __restrict__ acc, float* __restrict__ colsum)
{
  __shared__ float S[4][64];
  const int tid = threadIdx.x, lane = tid & 63, wave = tid >> 6;
  const int row = blockIdx.x * 4 + wave;   // 0..511
  const int b = row >> 3, ks = row & 7;

  float s0 = fmaf(expf(slsig[lane]), noise[row * 64 + lane], smu[lane]);
  slots[row * 64 + lane] = s0;
  acc[row * 64 + lane] = 0.f;
  if (lane == 0) colsum[row] = 0.f;

  float mu = wredsum(s0) * (1.f / 64.f);
  float dx = s0 - mu;
  float var = wredsum(dx * dx) * (1.f / 64.f);
  float sn = dx * rsqrtf(var + LN_EPS) * g_sl[lane] + b_sl[lane];
  S[wave][lane] = sn;
  __syncthreads();
  float qe = 0.f;
#pragma unroll 16
  for (int d = 0; d < 64; ++d) qe = fmaf(S[wave][d], wqT[d * 64 + lane], qe);
  // lane = d. B-frag: kb=d>>5, lrow=(d&31)>>3, j=d&7, col=ks (and zero col 8+ks)
  const int kb = lane >> 5, lrow = (lane & 31) >> 3, j = lane & 7;
  qF[((((b * 2 + kb) << 6) + (lrow << 4) + ks) << 3) + j] = f2bf(qe * 0.125f);
  qF[((((b * 2 + kb) << 6) + (lrow << 4) + 8 + ks) << 3) + j] = 0;
}

// ---------------------------------------------------------------------------
// K3: fused attention, all-MFMA. One 64-n chunk per wave; grid 1024 x 256.
// logits: 8 MFMAs (A=k frags, B=q frag) -> shuffle softmax over K=8 ->
// wave-private LDS transpose (C->A layout) -> PV: 8 MFMAs (B=v frags).
// Block LDS reduction -> 1 atomic per output.
__global__ __launch_bounds__(256) void k_attn(
    const ushortT* __restrict__ ktF, const ushortT* __restrict__ vF,
    const ushortT* __restrict__ qF,
    float* __restrict__ acc, float* __restrict__ colsum)
{
  __shared__ __align__(16) ushortT attnF[4][1024];  // per-wave P A-frags
  __shared__ float accLds[4][8][64];
  __shared__ float colLds[4][8];
  const int tid = threadIdx.x;
  const int lane = tid & 63;
  const int wave = tid >> 6;
  const int l15 = lane & 15, q = lane >> 4;
  const int b = blockIdx.x >> 4;
  const int chunk = ((blockIdx.x & 15) << 2) | wave;  // 0..63

  const ushortT* kbF = ktF + ((long)(b * 64 + chunk) << 12);
  const ushortT* vbF = vF + ((long)(b * 64 + chunk) << 12);

  short8 kA[4][2];
#pragma unroll
  for (int mt = 0; mt < 4; ++mt)
#pragma unroll
    for (int kb = 0; kb < 2; ++kb)
      kA[mt][kb] = *(const short8*)&kbF[((mt * 2 + kb) * 64 + lane) << 3];
  short8 qB[2];
#pragma unroll
  for (int kb = 0; kb < 2; ++kb)
    qB[kb] = *(const short8*)&qF[(((b * 2 + kb) << 6) + lane) << 3];

  f32x4 accL[4];
#pragma unroll
  for (int mt = 0; mt < 4; ++mt) {
    accL[mt] = (f32x4){0.f, 0.f, 0.f, 0.f};
    accL[mt] = __builtin_amdgcn_mfma_f32_16x16x32_bf16(kA[mt][0], qB[0], accL[mt], 0, 0, 0);
    accL[mt] = __builtin_amdgcn_mfma_f32_16x16x32_bf16(kA[mt][1], qB[1], accL[mt], 0, 0, 0);
  }

  short8 vB[4][2];
#pragma unroll
  for (int nt = 0; nt < 4; ++nt)
#pragma unroll
    for (int ks = 0; ks < 2; ++ks)
      vB[nt][ks] = *(const short8*)&vbF[((nt * 2 + ks) * 64 + lane) << 3];

  // softmax over slots (l15 subgroups of 8; cols 8..15 benign: q cols zeroed)
  // lane holds logits[n = chunk*64 + mt*16 + q*4 + r][slot l15]
  float csum = 0.f;
#pragma unroll
  for (int mt = 0; mt < 4; ++mt) {
    float av[4];
#pragma unroll
    for (int r = 0; r < 4; ++r) {
      float lv = accL[mt][r];
      float mx = lv;
      mx = fmaxf(mx, __shfl_xor(mx, 1));
      mx = fmaxf(mx, __shfl_xor(mx, 2));
      mx = fmaxf(mx, __shfl_xor(mx, 4));
      float ev = __expf(lv - mx);
      float sv = ev;
      sv += __shfl_xor(sv, 1); sv += __shfl_xor(sv, 2); sv += __shfl_xor(sv, 4);
      float a = ev * (1.f / sv) + EPS;
      av[r] = a;
      csum += a;
    }
    // transpose to A-frag: P[slot=l15][n]: frag=mt>>1,
    // lane'=((mt&1)*2+(q>>1))*16+l15, j0=(q&1)*4 (+r)
    us4 p = {f2bf(av[0]), f2bf(av[1]), f2bf(av[2]), f2bf(av[3])};
    *(us4*)&attnF[wave][((((mt >> 1) << 6) + (((mt & 1) * 2 + (q >> 1)) << 4)
                          + l15) << 3) + ((q & 1) << 2)] = p;
  }
  csum += __shfl_xor(csum, 16);
  csum += __shfl_xor(csum, 32);

  short8 pA0 = *(const short8*)&attnF[wave][(0 * 64 + lane) << 3];
  short8 pA1 = *(const short8*)&attnF[wave][(1 * 64 + lane) << 3];

  f32x4 accP[4];
#pragma unroll
  for (int nt = 0; nt < 4; ++nt) {
    accP[nt] = (f32x4){0.f, 0.f, 0.f, 0.f};
    accP[nt] = __builtin_amdgcn_mfma_f32_16x16x32_bf16(pA0, vB[nt][0], accP[nt], 0, 0, 0);
    accP[nt] = __builtin_amdgcn_mfma_f32_16x16x32_bf16(pA1, vB[nt][1], accP[nt], 0, 0, 0);
  }

  // C: row k = q*4+r (valid q<2), col d = nt*16 + l15
  if (q < 2) {
#pragma unroll
    for (int nt = 0; nt < 4; ++nt)
#pragma unroll
      for (int r = 0; r < 4; ++r)
        accLds[wave][q * 4 + r][nt * 16 + l15] = accP[nt][r];
  }
  if (q == 0 && l15 < 8) colLds[wave][l15] = csum;
  __syncthreads();

#pragma unroll
  for (int r = 0; r < 2; ++r) {
    const int o = tid + r * 256;     // 0..511 -> (k,d)
    const int kk = o >> 6, d = o & 63;
    float s = accLds[0][kk][d] + accLds[1][kk][d] + accLds[2][kk][d] + accLds[3][kk][d];
    atomicAdd(&acc[(b * 8 + kk) * 64 + d], s);
  }
  if (tid < 8) {
    float s = colLds[0][tid] + colLds[1][tid] + colLds[2][tid] + colLds[3][tid];
    atomicAdd(&colsum[b * 8 + tid], s);
  }
}

// ---------------------------------------------------------------------------
// K4: updates -> GRU -> LN -> MLP -> residual; emits next-iter q B-frag;
// zeroes acc/colsum. One wave per (b,k) row. grid 128 x 256.
__global__ __launch_bounds__(256) void k_update(
    float* __restrict__ acc, float* __restrict__ colsum,
    float* __restrict__ slots,
    const float* __restrict__ wihT, const float* __restrict__ whhT,
    const float* __restrict__ w1T, const float* __restrict__ w2T,
    const float* __restrict__ wqT,
    const float* __restrict__ b_ih, const float* __restrict__ b_hh,
    const float* __restrict__ mb1, const float* __restrict__ mb2,
    const float* __restrict__ g_ml, const float* __restrict__ b_ml,
    const float* __restrict__ g_sl, const float* __restrict__ b_sl,
    ushortT* __restrict__ qF, float* __restrict__ dout)
{
  __shared__ float S[4][256];
  const int tid = threadIdx.x, lane = tid & 63, wave = tid >> 6;
  const int row = blockIdx.x * 4 + wave;   // 0..511
  const int b = row >> 3, ks = row & 7;

  const float csum = colsum[row];
  const float u = acc[row * 64 + lane] / csum;
  const float h = slots[row * 64 + lane];
  acc[row * 64 + lane] = 0.f;            // ready for next k_attn
  if (lane == 0) colsum[row] = 0.f;

  float* Su = &S[wave][0];
  float* Sh = &S[wave][64];
  Su[lane] = u; Sh[lane] = h;
  __syncthreads();

  float gir = b_ih[lane], giz = b_ih[64 + lane], gin = b_ih[128 + lane];
  float ghr = b_hh[lane], ghz = b_hh[64 + lane], ghn = b_hh[128 + lane];
#pragma unroll 4
  for (int f = 0; f < 64; ++f) {
    const float uf = Su[f], hf = Sh[f];
    gir = fmaf(uf, wihT[f * 192 + lane], gir);
    giz = fmaf(uf, wihT[f * 192 + 64 + lane], giz);
    gin = fmaf(uf, wihT[f * 192 + 128 + lane], gin);
    ghr = fmaf(hf, whhT[f * 192 + lane], ghr);
    ghz = fmaf(hf, whhT[f * 192 + 64 + lane], ghz);
    ghn = fmaf(hf, whhT[f * 192 + 128 + lane], ghn);
  }
  const float r = 1.f / (1.f + expf(-(gir + ghr)));
  const float z = 1.f / (1.f + expf(-(giz + ghz)));
  const float nn = tanhf(fmaf(r, ghn, gin));
  const float hnew = (1.f - z) * nn + z * h;

  // LN (mlp)
  float mu = wredsum(hnew) * (1.f / 64.f);
  float dx = hnew - mu;
  float var = wredsum(dx * dx) * (1.f / 64.f);
  const float ln = dx * rsqrtf(var + LN_EPS) * g_ml[lane] + b_ml[lane];
  float* Sln = &S[wave][128];
  Sln[lane] = ln;
  __syncthreads();

  float h1a = mb1[lane], h1b = mb1[64 + lane];
#pragma unroll 4
  for (int f = 0; f < 64; ++f) {
    const float lf = Sln[f];
    h1a = fmaf(lf, w1T[f * 128 + lane], h1a);
    h1b = fmaf(lf, w1T[f * 128 + 64 + lane], h1b);
  }
  h1a = fmaxf(h1a, 0.f); h1b = fmaxf(h1b, 0.f);
  __syncthreads();                         // done reading Su/Sh region
  float* Shid = &S[wave][0];
  Shid[lane] = h1a; Shid[64 + lane] = h1b;
  __syncthreads();

  float o = mb2[lane];
#pragma unroll 4
  for (int j = 0; j < 128; ++j) o = fmaf(Shid[j], w2T[j * 64 + lane], o);
  const float snew = hnew + o;
  slots[row * 64 + lane] = snew;
  if (dout) dout[row * 64 + lane] = snew;

  // next-iteration q = LN_slots(snew) @ Wq^T * D^-0.5 -> bf16 B-frag
  float mu2 = wredsum(snew) * (1.f / 64.f);
  float dx2 = snew - mu2;
  float v2 = wredsum(dx2 * dx2) * (1.f / 64.f);
  const float sq = dx2 * rsqrtf(v2 + LN_EPS) * g_sl[lane] + b_sl[lane];
  __syncthreads();                         // done reading Sln
  float* Ssq = &S[wave][128];
  Ssq[lane] = sq;
  __syncthreads();
  float qe = 0.f;
#pragma unroll 16
  for (int d = 0; d < 64; ++d) qe = fmaf(Ssq[d], wqT[d * 64 + lane], qe);
  const int kb = lane >> 5, lrow = (lane & 31) >> 3, j = lane & 7;
  qF[((((b * 2 + kb) << 6) + (lrow << 4) + ks) << 3) + j] = f2bf(qe * 0.125f);
}

// ---------------------------------------------------------------------------
extern "C" void kernel_launch(void* const* d_in, const int* in_sizes, int n_in,
                              void* d_out, int out_size, void* d_ws, size_t ws_size,
                              hipStream_t stream) {
  const float* inp   = (const float*)d_in[0];
  const float* noise = (const float*)d_in[1];
  const float* smu   = (const float*)d_in[2];
  const float* slsig = (const float*)d_in[3];
  const float* Wq    = (const float*)d_in[4];
  const float* Wk    = (const float*)d_in[5];
  const float* Wv    = (const float*)d_in[6];
  const float* w_ih  = (const float*)d_in[7];
  const float* w_hh  = (const float*)d_in[8];
  const float* b_ih  = (const float*)d_in[9];
  const float* b_hh  = (const float*)d_in[10];
  const float* w1    = (const float*)d_in[11];
  const float* b1    = (const float*)d_in[12];
  const float* w2    = (const float*)d_in[13];
  const float* b2    = (const float*)d_in[14];
  const float* g_in  = (const float*)d_in[15];
  const float* bi_in = (const float*)d_in[16];
  const float* g_sl  = (const float*)d_in[17];
  const float* bi_sl = (const float*)d_in[18];
  const float* g_ml  = (const float*)d_in[19];
  const float* bi_ml = (const float*)d_in[20];

  float* ws      = (float*)d_ws;
  ushortT* ktF   = (ushortT*)(ws + OFF_KT);
  ushortT* vF    = (ushortT*)(ws + OFF_V);
  ushortT* qF    = (ushortT*)(ws + OFF_QT);
  float* ac      = ws + OFF_ACC;
  float* cs      = ws + OFF_COL;
  float* sl      = ws + OFF_SLOTS;
  float* wihT    = ws + OFF_WIHT;
  float* whhT    = ws + OFF_WHHT;
  float* w1T     = ws + OFF_W1T;
  float* w2T     = ws + OFF_W2T;
  float* wqT     = ws + OFF_WQT;
  ushortT* wpk   = (ushortT*)(ws + OFF_WKV);

  k_prep<<<208, 256, 0, stream>>>(w_ih, w_hh, w1, w2, Wq, Wk, Wv,
                                  wihT, whhT, w1T, w2T, wqT, wpk);
  k_ln_project<<<4096, 256, 0, stream>>>(inp, wpk, g_in, bi_in, ktF, vF);
  k_init<<<128, 256, 0, stream>>>(noise, smu, slsig, wqT, g_sl, bi_sl, sl, qF, ac, cs);
  for (int it = 0; it < 3; ++it) {
    k_attn<<<1024, 256, 0, stream>>>(ktF, vF, qF, ac, cs);
    k_update<<<128, 256, 0, stream>>>(ac, cs, sl, wihT, whhT, w1T, w2T, wqT,
                                      b_ih, b_hh, b1, b2, g_ml, bi_ml, g_sl, bi_sl,
                                      qF, it == 2 ? (float*)d_out : nullptr);
  }
}